// Round 10
// baseline (983.887 us; speedup 1.0000x reference)
//
#include <hip/hip_runtime.h>

#define B_ 1024
#define T_ 366
#define NS_ 365
#define CD_ 24
#define NCH 4

__device__ __forceinline__ float sigm(float x) { return __fdividef(1.f, 1.f + __expf(-x)); }
__device__ __forceinline__ float rl(float v, int k) {
    return __int_as_float(__builtin_amdgcn_readlane(__float_as_int(v), k));
}

// ---- pack: Wpk[e][32] = {w0..23, rad, bias}; Apk[r][32] = {w0..28, bias} ----
__global__ void mclstm_pack(const float* __restrict__ Wr, const float* __restrict__ br,
                            const float* __restrict__ Wp, const float* __restrict__ bp,
                            const float* __restrict__ Wc, const float* __restrict__ bc,
                            const float* __restrict__ Wa, const float* __restrict__ ba,
                            float* __restrict__ Wpk, float* __restrict__ Apk) {
    const int e = blockIdx.x * 64 + threadIdx.x;
    if (e < 576) {
#pragma unroll
        for (int k = 0; k < 24; ++k) Wpk[e * 32 + k] = Wr[e * 29 + k];
        Wpk[e * 32 + 24] = Wr[e * 29 + 25];
        Wpk[e * 32 + 25] = br[e];
#pragma unroll
        for (int k = 26; k < 32; ++k) Wpk[e * 32 + k] = 0.f;
    } else if (e < 625) {
        const int r = e - 576;
#pragma unroll
        for (int k = 0; k < 29; ++k)
            Apk[r * 32 + k] = (r < 24) ? Wp[r * 29 + k] : (r < 48) ? Wc[(r - 24) * 29 + k] : Wa[k];
        Apk[r * 32 + 29] = (r < 24) ? bp[r] : (r < 48) ? bc[r - 24] : ba[0];
        Apk[r * 32 + 30] = 0.f; Apk[r * 32 + 31] = 0.f;
    }
}

// ---- main: 4 chains/block, 512 thr, LDS weights (swizzled), zero global on path ----
__global__ __launch_bounds__(512, 1) void mclstm_main(
    const float* __restrict__ X, const float* __restrict__ ORY,
    const float* __restrict__ Wpk, const float* __restrict__ Apk,
    const float* __restrict__ c2a, const float* __restrict__ g2y,
    float* __restrict__ allday, float* __restrict__ Ccell, float* __restrict__ Cconv)
{
    __shared__ float4 Wl[576 * 8];          // granule-swizzled weight rows (73.7 KB)
    __shared__ float4 Al[49 * 8];           // aux rows (6.3 KB)
    __shared__ float zb[NCH][2][600];       // z, row-major stride 25
    __shared__ __align__(16) float pb[NCH][2][672];  // scaled P, col-major stride 28
    __shared__ __align__(16) float cbuf[NCH][24];
    __shared__ float cmb[NCH][24];
    __shared__ float rads[NCH];
    __shared__ float dvsb[NCH];

    const int tid = threadIdx.x;
    const int wv = tid >> 6, l = tid & 63;
    const int b0 = blockIdx.x * NCH;

    // ---- stage swizzled weights (coalesced b128) ----
    for (int g = tid; g < 576 * 8; g += 512) {
        const int e = g >> 3, q = g & 7;
        Wl[e * 8 + (q ^ (e & 7))] = ((const float4*)Wpk)[g];
    }
    for (int g = tid; g < 49 * 8; g += 512) {
        const int e = g >> 3, q = g & 7;
        Al[e * 8 + (q ^ (e & 7))] = ((const float4*)Apk)[g];
    }
    if (tid < NCH * 24) ((float*)cbuf)[tid] = 0.f;
    if (tid < NCH) rads[tid] = X[(size_t)(b0 + tid) * T_ * 4];
    if (wv < NCH && l < 7)
        allday[(size_t)(b0 + wv) * T_ * 7 + l] = ORY[(size_t)(b0 + wv) * T_ * 7 + l];

    // roles
    const bool isAux = (wv < 4);
    const int j = wv & 3;                                   // aux chain
    const float* xj = X + (size_t)(b0 + j) * T_ * 4;
    const float* oj = ORY + (size_t)(b0 + j) * T_ * 7;

    // B/C wave-aligned decode: wave = 2*chain + kind
    const int jBC = wv >> 1, kBC = wv & 1;
    const int rc = l >> 1, hh = l & 1;

    // allday constants (kind0 waves, even lanes; C_new[c] at lane 2c)
    const bool evn = ((l & 1) == 0) && (l < 48);
    const float c2 = (kBC == 0 && evn) ? c2a[l >> 1] : 0.f;
    const float gy = (kBC == 0 && evn && l >= 32) ? g2y[(l >> 1) - 16] : 0.f;

    // row-wave rows (wv>=4): e1 = s, e2 = s+256; every 4th lane: e3
    const int s = tid - 256;
    const int e1 = s, e2 = s + 256;
    const bool has3 = (!isAux) && ((l & 3) == 0);
    const int e3 = 512 + ((wv - 4) << 4) + (l >> 2);
    const int za1 = (e1 / 24) * 25 + e1 % 24;
    const int za2 = (e2 / 24) * 25 + e2 % 24;
    const int za3 = (e3 / 24) * 25 + e3 % 24;

    float4 cur = make_float4(0.f, 0.f, 0.f, 0.f);
    float dcur = 0.f;
    if (isAux) { cur = *(const float4*)xj; dcur = oj[0]; }

    __syncthreads();

    float Ncum = 0.f;
    float rp0 = 0.f, rp1 = 0.f, rp2 = 0.f, rp3 = 0.f;

    for (int u = 0; u <= NS_; ++u) {
        const bool do1 = (u < NS_), doCv = (u > 0);
        const float ra0 = rads[0], ra1 = rads[1], ra2 = rads[2], ra3 = rads[3];

        float4 nxt = cur; float dn = dcur;

        if (isAux) {
            // prefetch next step (off critical path; consumed after B1)
            const int un = (u + 1 <= NS_) ? (u + 1) : NS_;
            nxt = *(const float4*)(xj + un * 4);
            dn = oj[un * 7];
            if (do1) {
                // own-chain C
                float Csa[24];
#pragma unroll
                for (int q = 0; q < 6; ++q) {
                    const float4 v = ((const float4*)cbuf[j])[q];
                    Csa[4*q] = v.x; Csa[4*q+1] = v.y; Csa[4*q+2] = v.z; Csa[4*q+3] = v.w;
                }
                Ncum += cur.w;
                const float tave = 0.5f * (cur.y + cur.z);
                const float clm = fminf(fmaxf(tave * 50.f, 10.f), 40.f);
                const float eff = 0.54f - (clm - 10.f) * (0.18f / 30.f);
                const float cpot = cur.x * (eff * (2.f * 0.5f / 3.6f * (12.f / 44.f)));

                const int ar = (l < 49) ? l : 48;
                float au[32];
#pragma unroll
                for (int q = 0; q < 8; ++q) {
                    const float4 v = Al[ar * 8 + (q ^ (ar & 7))];
                    au[4*q] = v.x; au[4*q+1] = v.y; au[4*q+2] = v.z; au[4*q+3] = v.w;
                }
                float z = au[29];
#pragma unroll
                for (int k = 0; k < 24; ++k) z = fmaf(au[k], Csa[k], z);
                z = fmaf(au[24], dcur, z);
                z = fmaf(au[25], cur.x, z);
                z = fmaf(au[26], cur.y, z);
                z = fmaf(au[27], cur.z, z);
                z = fmaf(au[28], Ncum, z);

                float pm = (l < 24) ? z : -1e30f;
#pragma unroll
                for (int o = 1; o < 32; o <<= 1) pm = fmaxf(pm, __shfl_xor(pm, o, 32));
                float pe = (l < 24) ? __expf(z - pm) : 0.f;
                float ps = pe;
#pragma unroll
                for (int o = 1; o < 32; o <<= 1) ps += __shfl_xor(ps, o, 32);
                const float conz = __shfl(z, 24 + (l & 31), 64);
                const float asmz = __shfl(z, 48, 64);
                if (l < 24) {
                    const float part = __fdividef(pe, ps);
                    cmb[j][l] = (Csa[l] + sigm(asmz) * cpot * part) * (1.f - sigm(conz));
                }
            }
        } else {
            // all 4 chains' C (static indices)
            float Cs0[24], Cs1[24], Cs2[24], Cs3[24];
#pragma unroll
            for (int q = 0; q < 6; ++q) {
                const float4 v0 = ((const float4*)cbuf[0])[q];
                const float4 v1 = ((const float4*)cbuf[1])[q];
                const float4 v2 = ((const float4*)cbuf[2])[q];
                const float4 v3 = ((const float4*)cbuf[3])[q];
                Cs0[4*q]=v0.x; Cs0[4*q+1]=v0.y; Cs0[4*q+2]=v0.z; Cs0[4*q+3]=v0.w;
                Cs1[4*q]=v1.x; Cs1[4*q+1]=v1.y; Cs1[4*q+2]=v1.z; Cs1[4*q+3]=v1.w;
                Cs2[4*q]=v2.x; Cs2[4*q+1]=v2.y; Cs2[4*q+2]=v2.z; Cs2[4*q+3]=v2.w;
                Cs3[4*q]=v3.x; Cs3[4*q+1]=v3.y; Cs3[4*q+2]=v3.z; Cs3[4*q+3]=v3.w;
            }
#define ROW(E, ZA)                                                             \
            {                                                                  \
                float w[28];                                                   \
                _Pragma("unroll") for (int q = 0; q < 7; ++q) {                \
                    const float4 v = Wl[(E) * 8 + (q ^ ((E) & 7))];            \
                    w[4*q]=v.x; w[4*q+1]=v.y; w[4*q+2]=v.z; w[4*q+3]=v.w;      \
                }                                                              \
                float D0 = w[25], D1 = w[25], D2 = w[25], D3 = w[25];          \
                _Pragma("unroll") for (int k = 0; k < 24; ++k) {               \
                    D0 = fmaf(w[k], Cs0[k], D0); D1 = fmaf(w[k], Cs1[k], D1);  \
                    D2 = fmaf(w[k], Cs2[k], D2); D3 = fmaf(w[k], Cs3[k], D3);  \
                }                                                              \
                if (do1) {                                                     \
                    zb[0][0][ZA] = fmaf(w[24], ra0, D0);                       \
                    zb[1][0][ZA] = fmaf(w[24], ra1, D1);                       \
                    zb[2][0][ZA] = fmaf(w[24], ra2, D2);                       \
                    zb[3][0][ZA] = fmaf(w[24], ra3, D3);                       \
                }                                                              \
                if (doCv) {                                                    \
                    zb[0][1][ZA] = fmaf(w[24], rp0, D0);                       \
                    zb[1][1][ZA] = fmaf(w[24], rp1, D1);                       \
                    zb[2][1][ZA] = fmaf(w[24], rp2, D2);                       \
                    zb[3][1][ZA] = fmaf(w[24], rp3, D3);                       \
                }                                                              \
            }
            ROW(e1, za1)
            ROW(e2, za2)
            if (has3) ROW(e3, za3)
#undef ROW
        }
        __syncthreads();   // B1: zb + cmb ready

        // ---- Phase B: row softmax; wave (2j+kind), lanes: r = l>>1, h = l&1 ----
        {
            const bool act = (l < 48) && (kBC ? doCv : do1);
            if (act) {
                float z[12];
#pragma unroll
                for (int i = 0; i < 12; ++i) z[i] = zb[jBC][kBC][rc * 25 + hh * 12 + i];
                float m = z[0];
#pragma unroll
                for (int i = 1; i < 12; ++i) m = fmaxf(m, z[i]);
                m = fmaxf(m, __shfl_xor(m, 1));
                float ss = 0.f;
#pragma unroll
                for (int i = 0; i < 12; ++i) { z[i] = __expf(z[i] - m); ss += z[i]; }
                ss += __shfl_xor(ss, 1);
                const float mlt = kBC ? cbuf[jBC][rc] : cmb[jBC][rc];
                const float f = __fdividef(mlt, ss);
#pragma unroll
                for (int i = 0; i < 12; ++i) pb[jBC][kBC][(hh * 12 + i) * 28 + rc] = z[i] * f;
            }
            if (isAux && l == 0) { rads[j] = nxt.x; dvsb[j] = dn; }  // publish step u+1
        }
        __syncthreads();   // B2: pb + rads/dvsb ready

        // ---- Phase C: colsum; wave (2j+kind), 2 lanes/col ----
        {
            const bool act = (l < 48) && (kBC ? doCv : do1);
            float ssum = 0.f;
            if (act) {
                const float4* p4 = (const float4*)&pb[jBC][kBC][rc * 28 + hh * 12];
#pragma unroll
                for (int i = 0; i < 3; ++i) {
                    const float4 v = p4[i];
                    ssum += (v.x + v.y) + (v.z + v.w);
                }
                ssum += __shfl_xor(ssum, 1);
                if (hh == 0) {
                    if (kBC) {
                        Cconv[((size_t)(b0 + jBC) * NS_ + (u - 1)) * CD_ + rc] = ssum;
                    } else {
                        cbuf[jBC][rc] = ssum;
                        Ccell[((size_t)(b0 + jBC) * NS_ + u) * CD_ + rc] = ssum;
                    }
                }
            }
            if (kBC == 0 && do1) {
                const float cv = evn ? ssum : 0.f;
                const float pv = fabsf(cv * c2);
                const float yv = fabsf(cv * gy);
                float a16 = cv, p16 = pv, y16 = yv;
#pragma unroll
                for (int o = 1; o < 16; o <<= 1) {
                    a16 += __shfl_xor(a16, o, 16);
                    p16 += __shfl_xor(p16, o, 16);
                    y16 += __shfl_xor(y16, o, 16);
                }
                const float pai = rl(p16, 0) + rl(p16, 16) + rl(p16, 32);
                const float lea = rl(a16, 0)  * (1.f / 0.419f);
                const float ste = rl(a16, 16) * (1.f / 0.431f);
                const float gra = rl(a16, 32) * (1.f / 0.487f);
                const float yie = rl(y16, 32) * (1.f / 0.487f);
                const float agb = lea + ste + gra;
                const float dvsn = dvsb[jBC];
                if (l < 7) {
                    float val = dvsn;
                    val = (l == 1) ? pai : val;
                    val = (l == 2) ? lea : val;
                    val = (l == 3) ? ste : val;
                    val = (l == 4) ? gra : val;
                    val = (l == 5) ? agb : val;
                    val = (l == 6) ? yie : val;
                    allday[((size_t)(b0 + jBC) * T_ + (u + 1)) * 7 + l] = val;
                }
            }
        }
        __syncthreads();   // B3: cbuf(t+1) visible, zb free
        if (isAux) { cur = nxt; dcur = dn; }
        rp0 = ra0; rp1 = ra1; rp2 = ra2; rp3 = ra3;
    }
}

extern "C" void kernel_launch(void* const* d_in, const int* in_sizes, int n_in,
                              void* d_out, int out_size, void* d_ws, size_t ws_size,
                              hipStream_t stream) {
    const float* X   = (const float*)d_in[0];
    const float* ORY = (const float*)d_in[1];
    const float* Wr  = (const float*)d_in[2];
    const float* br  = (const float*)d_in[3];
    const float* Wp  = (const float*)d_in[4];
    const float* bp  = (const float*)d_in[5];
    const float* Wc  = (const float*)d_in[6];
    const float* bc  = (const float*)d_in[7];
    const float* Wa  = (const float*)d_in[8];
    const float* ba  = (const float*)d_in[9];
    const float* c2a = (const float*)d_in[10];
    const float* g2y = (const float*)d_in[11];

    float* allday = (float*)d_out;
    float* Ccell  = allday + (size_t)B_ * T_ * 7;
    float* Cconv  = Ccell + (size_t)B_ * NS_ * CD_;

    float* Wpk = (float*)d_ws;            // 576*32 floats
    float* Apk = Wpk + 576 * 32;          // 49*32 floats

    hipLaunchKernelGGL(mclstm_pack, dim3(10), dim3(64), 0, stream,
                       Wr, br, Wp, bp, Wc, bc, Wa, ba, Wpk, Apk);
    hipLaunchKernelGGL(mclstm_main, dim3(B_ / NCH), dim3(512), 0, stream,
                       X, ORY, Wpk, Apk, c2a, g2y, allday, Ccell, Cconv);
}